// Round 1
// baseline (4161.301 us; speedup 1.0000x reference)
//
#include <hip/hip_runtime.h>
#include <hip/hip_bf16.h>

#define G_   16
#define DG_  128
#define F_   2048
#define N_   2048
#define M_   2048

// ---------------- GEMM: C[Md x Nd] = A[Md x Kd] @ B[Nd x Kd]^T + bias ----
// (torch Linear layout: both operands row-major, contracted along K)
#define TILE 64
#define KT   16

__global__ __launch_bounds__(256)
void gemm_nt(const float* __restrict__ A, const float* __restrict__ B,
             const float* __restrict__ bias, float* __restrict__ C,
             int Md, int Nd, int Kd) {
  __shared__ float As[KT][TILE];
  __shared__ float Bs[KT][TILE];
  const int tx = threadIdx.x & 15;
  const int ty = threadIdx.x >> 4;
  const int row0 = blockIdx.y * TILE;
  const int col0 = blockIdx.x * TILE;
  float acc[4][4] = {};
  for (int k0 = 0; k0 < Kd; k0 += KT) {
#pragma unroll
    for (int j = 0; j < 4; ++j) {
      int idx = threadIdx.x + j * 256;   // 0..1023
      int m = idx >> 4;                  // /KT
      int k = idx & 15;                  // %KT
      As[k][m] = A[(size_t)(row0 + m) * Kd + k0 + k];
      Bs[k][m] = B[(size_t)(col0 + m) * Kd + k0 + k];
    }
    __syncthreads();
#pragma unroll
    for (int k = 0; k < KT; ++k) {
      float a[4], b[4];
#pragma unroll
      for (int i = 0; i < 4; ++i) a[i] = As[k][ty * 4 + i];
#pragma unroll
      for (int i = 0; i < 4; ++i) b[i] = Bs[k][tx * 4 + i];
#pragma unroll
      for (int i = 0; i < 4; ++i)
#pragma unroll
        for (int j = 0; j < 4; ++j)
          acc[i][j] = fmaf(a[i], b[j], acc[i][j]);
    }
    __syncthreads();
  }
#pragma unroll
  for (int i = 0; i < 4; ++i) {
    int r = row0 + ty * 4 + i;
#pragma unroll
    for (int j = 0; j < 4; ++j) {
      int c = col0 + tx * 4 + j;
      C[(size_t)r * Nd + c] = acc[i][j] + (bias ? bias[c] : 0.0f);
    }
  }
}

// ---------------- Attention: per (4 q-rows, group) block -----------------
// aff[n,g,m] = scale * dot(Q[n,g,:], K[m,g,:]) ; softmax over m ;
// out[n,g,d] = sum_m attn * V[m,g,d] + vb[g,d]
#define NB 4

__global__ __launch_bounds__(256)
void attn_fp32(const float* __restrict__ Q, const float* __restrict__ K,
               const float* __restrict__ V, const float* __restrict__ vb,
               float* __restrict__ out) {
  __shared__ float qs[NB][DG_];
  __shared__ float p[NB][M_];          // logits -> probs (32 KB)
  __shared__ float red[NB][4];
  __shared__ float red2[2][NB][128];
  const int tid = threadIdx.x;
  const int g = blockIdx.y;
  const int n0 = blockIdx.x * NB;

  for (int idx = tid; idx < NB * DG_; idx += 256) {
    int nb = idx >> 7, d = idx & (DG_ - 1);
    qs[nb][d] = Q[(size_t)(n0 + nb) * F_ + g * DG_ + d];
  }
  __syncthreads();

  const float scale = 0.08838834764831845f;  // 1/sqrt(128)

  // ---- logits ----
  for (int m = tid; m < M_; m += 256) {
    const float4* krow = (const float4*)(K + (size_t)m * F_ + g * DG_);
    float acc[NB] = {0.f, 0.f, 0.f, 0.f};
#pragma unroll 8
    for (int d4 = 0; d4 < DG_ / 4; ++d4) {
      float4 kv = krow[d4];
#pragma unroll
      for (int nb = 0; nb < NB; ++nb) {
        acc[nb] = fmaf(qs[nb][d4 * 4 + 0], kv.x, acc[nb]);
        acc[nb] = fmaf(qs[nb][d4 * 4 + 1], kv.y, acc[nb]);
        acc[nb] = fmaf(qs[nb][d4 * 4 + 2], kv.z, acc[nb]);
        acc[nb] = fmaf(qs[nb][d4 * 4 + 3], kv.w, acc[nb]);
      }
    }
#pragma unroll
    for (int nb = 0; nb < NB; ++nb) p[nb][m] = acc[nb] * scale;
  }
  __syncthreads();

  // ---- softmax max ----
  float vmax[NB];
#pragma unroll
  for (int nb = 0; nb < NB; ++nb) vmax[nb] = -1e30f;
  for (int m = tid; m < M_; m += 256)
#pragma unroll
    for (int nb = 0; nb < NB; ++nb) vmax[nb] = fmaxf(vmax[nb], p[nb][m]);
#pragma unroll
  for (int off = 32; off > 0; off >>= 1)
#pragma unroll
    for (int nb = 0; nb < NB; ++nb)
      vmax[nb] = fmaxf(vmax[nb], __shfl_xor(vmax[nb], off));
  if ((tid & 63) == 0)
#pragma unroll
    for (int nb = 0; nb < NB; ++nb) red[nb][tid >> 6] = vmax[nb];
  __syncthreads();
#pragma unroll
  for (int nb = 0; nb < NB; ++nb)
    vmax[nb] = fmaxf(fmaxf(red[nb][0], red[nb][1]),
                     fmaxf(red[nb][2], red[nb][3]));
  __syncthreads();   // before red reuse

  // ---- exp + sum ----
  float vsum[NB] = {0.f, 0.f, 0.f, 0.f};
  for (int m = tid; m < M_; m += 256)
#pragma unroll
    for (int nb = 0; nb < NB; ++nb) {
      float e = expf(p[nb][m] - vmax[nb]);
      p[nb][m] = e;
      vsum[nb] += e;
    }
#pragma unroll
  for (int off = 32; off > 0; off >>= 1)
#pragma unroll
    for (int nb = 0; nb < NB; ++nb) vsum[nb] += __shfl_xor(vsum[nb], off);
  if ((tid & 63) == 0)
#pragma unroll
    for (int nb = 0; nb < NB; ++nb) red[nb][tid >> 6] = vsum[nb];
  __syncthreads();
  float inv[NB];
#pragma unroll
  for (int nb = 0; nb < NB; ++nb)
    inv[nb] = 1.0f / (red[nb][0] + red[nb][1] + red[nb][2] + red[nb][3]);

  // ---- PV ----
  const int d = tid & 127;
  const int s = tid >> 7;
  float acc[NB] = {0.f, 0.f, 0.f, 0.f};
  for (int m = s; m < M_; m += 2) {
    float vv = V[(size_t)m * F_ + g * DG_ + d];
#pragma unroll
    for (int nb = 0; nb < NB; ++nb) acc[nb] = fmaf(p[nb][m], vv, acc[nb]);
  }
#pragma unroll
  for (int nb = 0; nb < NB; ++nb) red2[s][nb][d] = acc[nb];
  __syncthreads();
  if (s == 0) {
#pragma unroll
    for (int nb = 0; nb < NB; ++nb) {
      float o = (red2[0][nb][d] + red2[1][nb][d]) * inv[nb] + vb[g * DG_ + d];
      out[(size_t)(n0 + nb) * F_ + g * DG_ + d] = o;
    }
  }
}

extern "C" void kernel_launch(void* const* d_in, const int* in_sizes, int n_in,
                              void* d_out, int out_size, void* d_ws, size_t ws_size,
                              hipStream_t stream) {
  const float* roi  = (const float*)d_in[0];
  const float* ref  = (const float*)d_in[1];
  const float* Wq_w = (const float*)d_in[2];
  const float* Wq_b = (const float*)d_in[3];
  const float* Wk_w = (const float*)d_in[4];
  const float* Wk_b = (const float*)d_in[5];
  const float* Wv_w = (const float*)d_in[6];
  const float* Wv_b = (const float*)d_in[7];
  float* out = (float*)d_out;

  if (ws_size < 3ull * N_ * F_ * sizeof(float)) return;  // need 48 MB scratch
  float* Qb = (float*)d_ws;
  float* Kb = Qb + (size_t)N_ * F_;
  float* Vb = Kb + (size_t)M_ * F_;

  dim3 gg(F_ / TILE, N_ / TILE);   // 32 x 32
  // Q = roi @ Wq^T + bq ; K = ref @ Wk^T + bk ; V = ref @ Wv^T
  gemm_nt<<<gg, 256, 0, stream>>>(roi, Wq_w, Wq_b, Qb, N_, F_, F_);
  gemm_nt<<<gg, 256, 0, stream>>>(ref, Wk_w, Wk_b, Kb, M_, F_, F_);
  gemm_nt<<<gg, 256, 0, stream>>>(ref, Wv_w, nullptr, Vb, M_, F_, F_);

  attn_fp32<<<dim3(N_ / NB, G_), 256, 0, stream>>>(Qb, Kb, Vb, Wv_b, out);
}

// Round 2
// 350.839 us; speedup vs baseline: 11.8610x; 11.8610x over previous
//
#include <hip/hip_runtime.h>
#include <hip/hip_bf16.h>

#define G_   16
#define DG_  128
#define F_   2048
#define N_   2048
#define M_   2048

typedef __attribute__((ext_vector_type(8))) short s16x8;   // 8 bf16 (4 VGPRs)
typedef __attribute__((ext_vector_type(4))) float f32x4;

typedef const __attribute__((address_space(1))) void GV;
typedef __attribute__((address_space(3))) void LV;

__device__ inline unsigned short f2bf(float f) {           // RN-even fp32->bf16
  unsigned u = __float_as_uint(f);
  u += 0x7fffu + ((u >> 16) & 1u);
  return (unsigned short)(u >> 16);
}

// ---------------- fp32 -> bf16 convert, 8 elems/thread -------------------
__global__ __launch_bounds__(256)
void cvt_bf16(const float* __restrict__ s, unsigned short* __restrict__ d, int n8) {
  int i = blockIdx.x * 256 + threadIdx.x;
  if (i >= n8) return;
  const float4* sp = (const float4*)(s + (size_t)i * 8);
  float4 a = sp[0], b = sp[1];
  uint4 o;
  o.x = (unsigned)f2bf(a.x) | ((unsigned)f2bf(a.y) << 16);
  o.y = (unsigned)f2bf(a.z) | ((unsigned)f2bf(a.w) << 16);
  o.z = (unsigned)f2bf(b.x) | ((unsigned)f2bf(b.y) << 16);
  o.w = (unsigned)f2bf(b.z) | ((unsigned)f2bf(b.w) << 16);
  *(uint4*)(d + (size_t)i * 8) = o;
}

// ---------------- bf16 NT GEMM: C[m][n] = sum_k A[m][k]*B[n][k] + bias ---
// 128x128 tile, BK=32, 4 waves, 16x16x32 MFMA, global_load_lds staging.
__global__ __launch_bounds__(256)
void gemm_nt_bf16(const unsigned short* __restrict__ A,
                  const unsigned short* __restrict__ B,
                  const float* __restrict__ bias,
                  unsigned short* __restrict__ C, int Kd, int Nd) {
  __shared__ unsigned short As[128 * 32];
  __shared__ unsigned short Bs[128 * 32];
  const int tid = threadIdx.x;
  const int lane = tid & 63;
  const int wv = tid >> 6;
  const int wm = wv >> 1, wn = wv & 1;
  const int l15 = lane & 15, l4 = lane >> 4;
  const int m0 = blockIdx.y * 128, n0 = blockIdx.x * 128;

  f32x4 acc[4][4];
#pragma unroll
  for (int i = 0; i < 4; ++i)
#pragma unroll
    for (int j = 0; j < 4; ++j) acc[i][j] = (f32x4){0.f, 0.f, 0.f, 0.f};

  const unsigned short* ga = A + (size_t)(m0 + (tid >> 2)) * Kd + (tid & 3) * 8;
  const unsigned short* gb = B + (size_t)(n0 + (tid >> 2)) * Kd + (tid & 3) * 8;
  char* lA = (char*)As + wv * 1024;
  char* lB = (char*)Bs + wv * 1024;

  for (int k0 = 0; k0 < Kd; k0 += 32) {
    __builtin_amdgcn_global_load_lds((GV*)(ga + k0),            (LV*)lA,          16, 0, 0);
    __builtin_amdgcn_global_load_lds((GV*)(ga + 64 * Kd + k0),  (LV*)(lA + 4096), 16, 0, 0);
    __builtin_amdgcn_global_load_lds((GV*)(gb + k0),            (LV*)lB,          16, 0, 0);
    __builtin_amdgcn_global_load_lds((GV*)(gb + 64 * Kd + k0),  (LV*)(lB + 4096), 16, 0, 0);
    __syncthreads();

    s16x8 af[4], bf[4];
#pragma unroll
    for (int i = 0; i < 4; ++i)
      af[i] = *(const s16x8*)(As + (wm * 64 + i * 16 + l15) * 32 + l4 * 8);
#pragma unroll
    for (int i = 0; i < 4; ++i)
      bf[i] = *(const s16x8*)(Bs + (wn * 64 + i * 16 + l15) * 32 + l4 * 8);
#pragma unroll
    for (int am = 0; am < 4; ++am)
#pragma unroll
      for (int bn = 0; bn < 4; ++bn)
        acc[am][bn] = __builtin_amdgcn_mfma_f32_16x16x32_bf16(af[am], bf[bn], acc[am][bn], 0, 0, 0);
    __syncthreads();
  }

#pragma unroll
  for (int bn = 0; bn < 4; ++bn) {
    int c = n0 + wn * 64 + bn * 16 + l15;
    float bv = bias ? bias[c] : 0.f;
#pragma unroll
    for (int am = 0; am < 4; ++am) {
#pragma unroll
      for (int j = 0; j < 4; ++j) {
        int r = m0 + wm * 64 + am * 16 + l4 * 4 + j;
        C[(size_t)r * Nd + c] = f2bf(acc[am][bn][j] + bv);
      }
    }
  }
}

// ---------------- flash attention, bf16 MFMA -----------------------------
// Block: (64 q-rows, 1 group); 4 waves x 16 q-rows; KV tiles of 64.
__global__ __launch_bounds__(256)
void attn_mfma(const unsigned short* __restrict__ Q,
               const unsigned short* __restrict__ K,
               const unsigned short* __restrict__ V,
               const float* __restrict__ vb,
               float* __restrict__ out) {
  __shared__ unsigned short Kt[64 * 136];   // [kv][128 + 8 pad]
  __shared__ unsigned short Vt[64 * 136];
  __shared__ unsigned short Pt[4][16 * 72]; // per-wave P [16 q][64 kv + 8 pad]
  const int tid = threadIdx.x, lane = tid & 63, wv = tid >> 6;
  const int l15 = lane & 15, l4 = lane >> 4;
  const int g = blockIdx.y;
  const int q0 = blockIdx.x * 64 + wv * 16;

  // Q A-fragments from global (row = l15, k = kc*32 + l4*8 + e)
  s16x8 qa[4];
#pragma unroll
  for (int kc = 0; kc < 4; ++kc)
    qa[kc] = *(const s16x8*)(Q + (size_t)(q0 + l15) * F_ + g * DG_ + kc * 32 + l4 * 8);

  f32x4 oa[8];
#pragma unroll
  for (int df = 0; df < 8; ++df) oa[df] = (f32x4){0.f, 0.f, 0.f, 0.f};
  float m_r[4], l_r[4];
#pragma unroll
  for (int j = 0; j < 4; ++j) { m_r[j] = -1e30f; l_r[j] = 0.f; }

  const float cscale = 0.12751665f;  // (1/sqrt(128)) * log2(e)

  for (int kv0 = 0; kv0 < M_; kv0 += 64) {
    // ---- stage K,V tiles (reg-staged, padded rows) ----
#pragma unroll
    for (int i = 0; i < 4; ++i) {
      int kv = i * 16 + (tid >> 4);
      int d0 = (tid & 15) * 8;
      size_t gsrc = (size_t)(kv0 + kv) * F_ + g * DG_ + d0;
      *(uint4*)((char*)Kt + kv * 272 + d0 * 2) = *(const uint4*)(K + gsrc);
      *(uint4*)((char*)Vt + kv * 272 + d0 * 2) = *(const uint4*)(V + gsrc);
    }
    __syncthreads();

    // ---- S = Q K^T (16q x 64kv per wave) ----
    f32x4 sf[4];
#pragma unroll
    for (int kvf = 0; kvf < 4; ++kvf) {
      f32x4 s = (f32x4){0.f, 0.f, 0.f, 0.f};
#pragma unroll
      for (int kc = 0; kc < 4; ++kc) {
        s16x8 bk = *(const s16x8*)((char*)Kt + (kvf * 16 + l15) * 272 + kc * 64 + l4 * 16);
        s = __builtin_amdgcn_mfma_f32_16x16x32_bf16(qa[kc], bk, s, 0, 0, 0);
      }
      sf[kvf] = s;
    }

    // ---- online softmax (rows live across 16-lane groups) ----
    float mt[4], corr[4];
#pragma unroll
    for (int j = 0; j < 4; ++j) {
      float t = fmaxf(fmaxf(sf[0][j], sf[1][j]), fmaxf(sf[2][j], sf[3][j]));
#pragma unroll
      for (int off = 1; off < 16; off <<= 1) t = fmaxf(t, __shfl_xor(t, off));
      mt[j] = t * cscale;
      float mn = fmaxf(m_r[j], mt[j]);
      corr[j] = exp2f(m_r[j] - mn);
      m_r[j] = mn;
      l_r[j] *= corr[j];
    }
    float ps[4] = {0.f, 0.f, 0.f, 0.f};
#pragma unroll
    for (int kvf = 0; kvf < 4; ++kvf) {
#pragma unroll
      for (int j = 0; j < 4; ++j) {
        float p = exp2f(sf[kvf][j] * cscale - m_r[j]);
        ps[j] += p;
        Pt[wv][(l4 * 4 + j) * 72 + kvf * 16 + l15] = f2bf(p);
      }
    }
#pragma unroll
    for (int j = 0; j < 4; ++j) {
      float t = ps[j];
#pragma unroll
      for (int off = 1; off < 16; off <<= 1) t += __shfl_xor(t, off);
      l_r[j] += t;
    }
#pragma unroll
    for (int df = 0; df < 8; ++df)
#pragma unroll
      for (int j = 0; j < 4; ++j) oa[df][j] *= corr[j];

    // ---- O += P V ----
    s16x8 pa[2];
#pragma unroll
    for (int kc2 = 0; kc2 < 2; ++kc2)
      pa[kc2] = *(const s16x8*)(&Pt[wv][l15 * 72 + kc2 * 32 + l4 * 8]);
#pragma unroll
    for (int df = 0; df < 8; ++df) {
#pragma unroll
      for (int kc2 = 0; kc2 < 2; ++kc2) {
        s16x8 vf;
#pragma unroll
        for (int e = 0; e < 8; ++e)
          vf[e] = (short)Vt[(kc2 * 32 + l4 * 8 + e) * 136 + df * 16 + l15];
        oa[df] = __builtin_amdgcn_mfma_f32_16x16x32_bf16(pa[kc2], vf, oa[df], 0, 0, 0);
      }
    }
    __syncthreads();
  }

  // ---- epilogue: normalize + bias ----
#pragma unroll
  for (int df = 0; df < 8; ++df) {
    int c = g * DG_ + df * 16 + l15;
    float bv = vb[c];
#pragma unroll
    for (int j = 0; j < 4; ++j) {
      int r = q0 + l4 * 4 + j;
      out[(size_t)r * F_ + c] = oa[df][j] / l_r[j] + bv;
    }
  }
}

extern "C" void kernel_launch(void* const* d_in, const int* in_sizes, int n_in,
                              void* d_out, int out_size, void* d_ws, size_t ws_size,
                              hipStream_t stream) {
  const float* roi  = (const float*)d_in[0];
  const float* ref  = (const float*)d_in[1];
  const float* Wq_w = (const float*)d_in[2];
  const float* Wq_b = (const float*)d_in[3];
  const float* Wk_w = (const float*)d_in[4];
  const float* Wk_b = (const float*)d_in[5];
  const float* Wv_w = (const float*)d_in[6];
  const float* Wv_b = (const float*)d_in[7];
  float* out = (float*)d_out;

  if (ws_size < 48ull * 1024 * 1024) return;
  unsigned short* roi_bf = (unsigned short*)d_ws;       // 6 x 8 MB
  unsigned short* ref_bf = roi_bf + 4194304;
  unsigned short* W_bf   = ref_bf + 4194304;
  unsigned short* Qb     = W_bf   + 4194304;
  unsigned short* Kb     = Qb     + 4194304;
  unsigned short* Vb     = Kb     + 4194304;

  const int n8 = (N_ * F_) / 8;  // 524288
  cvt_bf16<<<2048, 256, 0, stream>>>(roi,  roi_bf, n8);
  cvt_bf16<<<2048, 256, 0, stream>>>(ref,  ref_bf, n8);

  dim3 gg(16, 16);
  cvt_bf16<<<2048, 256, 0, stream>>>(Wq_w, W_bf, n8);
  gemm_nt_bf16<<<gg, 256, 0, stream>>>(roi_bf, W_bf, Wq_b, Qb, F_, F_);
  cvt_bf16<<<2048, 256, 0, stream>>>(Wk_w, W_bf, n8);
  gemm_nt_bf16<<<gg, 256, 0, stream>>>(ref_bf, W_bf, Wk_b, Kb, F_, F_);
  cvt_bf16<<<2048, 256, 0, stream>>>(Wv_w, W_bf, n8);
  gemm_nt_bf16<<<gg, 256, 0, stream>>>(ref_bf, W_bf, nullptr, Vb, F_, F_);

  attn_mfma<<<dim3(N_ / 64, G_), 256, 0, stream>>>(Qb, Kb, Vb, Wv_b, out);
}

// Round 3
// 215.825 us; speedup vs baseline: 19.2809x; 1.6256x over previous
//
#include <hip/hip_runtime.h>
#include <hip/hip_bf16.h>

#define G_   16
#define DG_  128
#define F_   2048
#define N_   2048
#define M_   2048

typedef __attribute__((ext_vector_type(8))) short s16x8;   // 8 bf16 (4 VGPRs)
typedef __attribute__((ext_vector_type(4))) float f32x4;
typedef __attribute__((ext_vector_type(2))) unsigned int u32x2;

typedef const __attribute__((address_space(1))) void GV;
typedef __attribute__((address_space(3))) void LV;

__device__ inline unsigned short f2bf(float f) {           // RN-even fp32->bf16
  unsigned u = __float_as_uint(f);
  u += 0x7fffu + ((u >> 16) & 1u);
  return (unsigned short)(u >> 16);
}

// ---------------- fp32 -> bf16 convert, 8 elems/thread -------------------
__global__ __launch_bounds__(256)
void cvt_bf16(const float* __restrict__ s, unsigned short* __restrict__ d, int n8) {
  int i = blockIdx.x * 256 + threadIdx.x;
  if (i >= n8) return;
  const float4* sp = (const float4*)(s + (size_t)i * 8);
  float4 a = sp[0], b = sp[1];
  uint4 o;
  o.x = (unsigned)f2bf(a.x) | ((unsigned)f2bf(a.y) << 16);
  o.y = (unsigned)f2bf(a.z) | ((unsigned)f2bf(a.w) << 16);
  o.z = (unsigned)f2bf(b.x) | ((unsigned)f2bf(b.y) << 16);
  o.w = (unsigned)f2bf(b.z) | ((unsigned)f2bf(b.w) << 16);
  *(uint4*)(d + (size_t)i * 8) = o;
}

// ---------------- bf16 NT GEMM: C[m][n] = sum_k A[m][k]*B[n][k] + bias ---
// 128x128 tile, BK=64, 2-phase prefetch, XOR-swizzled LDS ([128][64] rows),
// pre-swizzled global source for global_load_lds (write-linear == read-swz).
__global__ __launch_bounds__(256)
void gemm_nt_bf16(const unsigned short* __restrict__ A,
                  const unsigned short* __restrict__ B,
                  const float* __restrict__ bias,
                  unsigned short* __restrict__ C, int Kd, int Nd) {
  __shared__ unsigned short As[2][128 * 64];
  __shared__ unsigned short Bs[2][128 * 64];
  const int tid = threadIdx.x, lane = tid & 63, wv = tid >> 6;
  const int wm = wv >> 1, wn = wv & 1;
  const int l15 = lane & 15, l4 = lane >> 4;
  const int m0 = blockIdx.y * 128, n0 = blockIdx.x * 128;

  f32x4 acc[4][4];
#pragma unroll
  for (int i = 0; i < 4; ++i)
#pragma unroll
    for (int j = 0; j < 4; ++j) acc[i][j] = (f32x4){0.f, 0.f, 0.f, 0.f};

  // pre-swizzled global k-offset so linear lane*16B LDS writes land swizzled
  const int ksw = (((lane & 7) ^ (lane >> 3)) * 8);
  const size_t baseA = (size_t)(m0 + wv * 32 + (lane >> 3)) * Kd + ksw;
  const size_t baseB = (size_t)(n0 + wv * 32 + (lane >> 3)) * Kd + ksw;

  auto stage = [&](int buf, int k0) {
#pragma unroll
    for (int i = 0; i < 4; ++i) {
      __builtin_amdgcn_global_load_lds((GV*)(A + baseA + (size_t)i * 8 * Kd + k0),
                                       (LV*)(&As[buf][(wv * 32 + i * 8) * 64]), 16, 0, 0);
      __builtin_amdgcn_global_load_lds((GV*)(B + baseB + (size_t)i * 8 * Kd + k0),
                                       (LV*)(&Bs[buf][(wv * 32 + i * 8) * 64]), 16, 0, 0);
    }
  };

  stage(0, 0);
  __syncthreads();
  int cur = 0;
  const int xorb = (l15 & 7) << 4;
  const int csw0 = (l4 * 16) ^ xorb;
  const int csw1 = (64 + l4 * 16) ^ xorb;

  const int NT = Kd / 64;
  for (int t = 0; t < NT; ++t) {
    if (t + 1 < NT) stage(cur ^ 1, (t + 1) * 64);
    const unsigned short* Ab = &As[cur][0];
    const unsigned short* Bb = &Bs[cur][0];
#pragma unroll
    for (int kc = 0; kc < 2; ++kc) {
      const int cs = kc ? csw1 : csw0;
      s16x8 af[4], bf[4];
#pragma unroll
      for (int i = 0; i < 4; ++i)
        af[i] = *(const s16x8*)((const char*)Ab + (wm * 64 + i * 16 + l15) * 128 + cs);
#pragma unroll
      for (int i = 0; i < 4; ++i)
        bf[i] = *(const s16x8*)((const char*)Bb + (wn * 64 + i * 16 + l15) * 128 + cs);
#pragma unroll
      for (int am = 0; am < 4; ++am)
#pragma unroll
        for (int bn = 0; bn < 4; ++bn)
          acc[am][bn] = __builtin_amdgcn_mfma_f32_16x16x32_bf16(af[am], bf[bn], acc[am][bn], 0, 0, 0);
    }
    __syncthreads();
    cur ^= 1;
  }

#pragma unroll
  for (int bn = 0; bn < 4; ++bn) {
    int c = n0 + wn * 64 + bn * 16 + l15;
    float bv = bias ? bias[c] : 0.f;
#pragma unroll
    for (int am = 0; am < 4; ++am) {
#pragma unroll
      for (int j = 0; j < 4; ++j) {
        int r = m0 + wm * 64 + am * 16 + l4 * 4 + j;
        C[(size_t)r * Nd + c] = f2bf(acc[am][bn][j] + bv);
      }
    }
  }
}

// ---------------- flash attention, bf16 MFMA, swapped QK^T ---------------
// Block: (64 q, 1 group) = 4 waves x 16 q. KV tiles of 64, double-buffered.
// Kt[64][128] (256B rows), Vts[128][64] (V^T, 128B rows), Pt per-wave [16][64].
// All tiles XOR-swizzled: byte ^= ((row&7)<<4).
__global__ __launch_bounds__(256)
void attn_mfma(const unsigned short* __restrict__ Q,
               const unsigned short* __restrict__ K,
               const unsigned short* __restrict__ Vt,
               const float* __restrict__ vb,
               float* __restrict__ out) {
  __shared__ unsigned short Kt[2][64 * 128];
  __shared__ unsigned short Vts[2][128 * 64];
  __shared__ unsigned short Pt[4][16 * 64];
  const int tid = threadIdx.x, lane = tid & 63, wv = tid >> 6;
  const int l15 = lane & 15, l4 = lane >> 4;
  const int g = blockIdx.y;
  const int q0 = blockIdx.x * 64 + wv * 16;

  // Q fragments (A/B row layout: row=l15, k = kc*32 + l4*8 + e)
  s16x8 qa[4];
#pragma unroll
  for (int kc = 0; kc < 4; ++kc)
    qa[kc] = *(const s16x8*)(Q + (size_t)(q0 + l15) * F_ + g * DG_ + kc * 32 + l4 * 8);

  f32x4 oa[8];
#pragma unroll
  for (int df = 0; df < 8; ++df) oa[df] = (f32x4){0.f, 0.f, 0.f, 0.f};
  float m_r = -1e30f, l_r = 0.f;
  const float cscale = 0.12751664508246770f;  // (1/sqrt(128)) * log2(e)

  // pre-swizzled global offsets for global_load_lds staging
  const int ksw0 = (((lane & 15) ^ (lane >> 4)) * 8);
  const int ksw1 = (((lane & 15) ^ 4 ^ (lane >> 4)) * 8);
  const int vsw  = (((lane & 7) ^ (lane >> 3)) * 8);
  const int xorb = (l15 & 7) << 4;
  int csw[4];
#pragma unroll
  for (int kc = 0; kc < 4; ++kc) csw[kc] = (kc * 64 + l4 * 16) ^ xorb;

  auto stage = [&](int buf, int kv0) {
#pragma unroll
    for (int i = 0; i < 4; ++i) {   // K tile: 4 rows (256B) per instr
      int r0 = wv * 16 + i * 4;
      __builtin_amdgcn_global_load_lds(
          (GV*)(K + (size_t)(kv0 + r0 + (lane >> 4)) * F_ + g * DG_ + ((i & 1) ? ksw1 : ksw0)),
          (LV*)(&Kt[buf][r0 * 128]), 16, 0, 0);
    }
#pragma unroll
    for (int i = 0; i < 4; ++i) {   // V^T tile: 8 rows (128B) per instr
      int r0 = wv * 32 + i * 8;
      __builtin_amdgcn_global_load_lds(
          (GV*)(Vt + (size_t)(g * DG_ + r0 + (lane >> 3)) * M_ + kv0 + vsw),
          (LV*)(&Vts[buf][r0 * 64]), 16, 0, 0);
    }
  };

  stage(0, 0);
  __syncthreads();
  int cur = 0;
  unsigned short* Pw = &Pt[wv][0];

  for (int t = 0; t < M_ / 64; ++t) {
    if (t + 1 < M_ / 64) stage(cur ^ 1, (t + 1) * 64);
    const unsigned short* Kb = &Kt[cur][0];
    const unsigned short* Vb = &Vts[cur][0];

    // ---- S^T = K Q^T : D[kv][q], lane: q=l15, kv = kvf*16 + l4*4 + j ----
    f32x4 sf[4];
#pragma unroll
    for (int kvf = 0; kvf < 4; ++kvf) {
      f32x4 s = (f32x4){0.f, 0.f, 0.f, 0.f};
#pragma unroll
      for (int kc = 0; kc < 4; ++kc) {
        s16x8 kf = *(const s16x8*)((const char*)Kb + (kvf * 16 + l15) * 256 + csw[kc]);
        s = __builtin_amdgcn_mfma_f32_16x16x32_bf16(kf, qa[kc], s, 0, 0, 0);
      }
      sf[kvf] = s;
    }

    // ---- online softmax, row = q = l15 (4-lane-group reduce) ----
    float tmax = sf[0][0];
#pragma unroll
    for (int kvf = 0; kvf < 4; ++kvf)
#pragma unroll
      for (int j = 0; j < 4; ++j) tmax = fmaxf(tmax, sf[kvf][j]);
    tmax = fmaxf(tmax, __shfl_xor(tmax, 16));
    tmax = fmaxf(tmax, __shfl_xor(tmax, 32));
    float mnew = fmaxf(m_r, tmax * cscale);
    float corr = exp2f(m_r - mnew);
    m_r = mnew;

    float psum = 0.f;
#pragma unroll
    for (int kvf = 0; kvf < 4; ++kvf) {
      float p0 = exp2f(sf[kvf][0] * cscale - mnew);
      float p1 = exp2f(sf[kvf][1] * cscale - mnew);
      float p2 = exp2f(sf[kvf][2] * cscale - mnew);
      float p3 = exp2f(sf[kvf][3] * cscale - mnew);
      psum += (p0 + p1) + (p2 + p3);
      u32x2 w;
      w.x = (unsigned)f2bf(p0) | ((unsigned)f2bf(p1) << 16);
      w.y = (unsigned)f2bf(p2) | ((unsigned)f2bf(p3) << 16);
      *(u32x2*)((char*)Pw + l15 * 128 + ((kvf * 32 + l4 * 8) ^ xorb)) = w;
    }
    psum += __shfl_xor(psum, 16);
    psum += __shfl_xor(psum, 32);
    l_r = l_r * corr + psum;

    // ---- rescale O (O layout: d = l15, q = l4*4 + j) ----
    float c0 = __shfl(corr, l4 * 4 + 0);
    float c1 = __shfl(corr, l4 * 4 + 1);
    float c2 = __shfl(corr, l4 * 4 + 2);
    float c3 = __shfl(corr, l4 * 4 + 3);
#pragma unroll
    for (int df = 0; df < 8; ++df) {
      oa[df][0] *= c0; oa[df][1] *= c1; oa[df][2] *= c2; oa[df][3] *= c3;
    }

    // ---- O += P V : A = P rows (q=l15), B = V^T rows (d) ----
    s16x8 pa0 = *(const s16x8*)((const char*)Pw + l15 * 128 + csw[0]);
    s16x8 pa1 = *(const s16x8*)((const char*)Pw + l15 * 128 + csw[1]);
#pragma unroll
    for (int df = 0; df < 8; ++df) {
      s16x8 v0 = *(const s16x8*)((const char*)Vb + (df * 16 + l15) * 128 + csw[0]);
      s16x8 v1 = *(const s16x8*)((const char*)Vb + (df * 16 + l15) * 128 + csw[1]);
      oa[df] = __builtin_amdgcn_mfma_f32_16x16x32_bf16(pa0, v0, oa[df], 0, 0, 0);
      oa[df] = __builtin_amdgcn_mfma_f32_16x16x32_bf16(pa1, v1, oa[df], 0, 0, 0);
    }
    __syncthreads();
    cur ^= 1;
  }

  // ---- epilogue ----
  float linv = 1.0f / l_r;
  float i0 = __shfl(linv, l4 * 4 + 0);
  float i1 = __shfl(linv, l4 * 4 + 1);
  float i2 = __shfl(linv, l4 * 4 + 2);
  float i3 = __shfl(linv, l4 * 4 + 3);
#pragma unroll
  for (int df = 0; df < 8; ++df) {
    int c = g * DG_ + df * 16 + l15;
    float bv = vb[c];
    out[(size_t)(q0 + l4 * 4 + 0) * F_ + c] = oa[df][0] * i0 + bv;
    out[(size_t)(q0 + l4 * 4 + 1) * F_ + c] = oa[df][1] * i1 + bv;
    out[(size_t)(q0 + l4 * 4 + 2) * F_ + c] = oa[df][2] * i2 + bv;
    out[(size_t)(q0 + l4 * 4 + 3) * F_ + c] = oa[df][3] * i3 + bv;
  }
}

extern "C" void kernel_launch(void* const* d_in, const int* in_sizes, int n_in,
                              void* d_out, int out_size, void* d_ws, size_t ws_size,
                              hipStream_t stream) {
  const float* roi  = (const float*)d_in[0];
  const float* ref  = (const float*)d_in[1];
  const float* Wq_w = (const float*)d_in[2];
  const float* Wq_b = (const float*)d_in[3];
  const float* Wk_w = (const float*)d_in[4];
  const float* Wk_b = (const float*)d_in[5];
  const float* Wv_w = (const float*)d_in[6];
  const float* Wv_b = (const float*)d_in[7];
  float* out = (float*)d_out;

  if (ws_size < 48ull * 1024 * 1024) return;
  unsigned short* roi_bf = (unsigned short*)d_ws;       // 6 x 8 MB
  unsigned short* ref_bf = roi_bf + 4194304;
  unsigned short* W_bf   = ref_bf + 4194304;
  unsigned short* Qb     = W_bf   + 4194304;
  unsigned short* Kb     = Qb     + 4194304;
  unsigned short* Vtb    = Kb     + 4194304;

  const int n8 = (N_ * F_) / 8;  // 524288
  cvt_bf16<<<2048, 256, 0, stream>>>(roi, roi_bf, n8);
  cvt_bf16<<<2048, 256, 0, stream>>>(ref, ref_bf, n8);

  dim3 gg(16, 16);
  cvt_bf16<<<2048, 256, 0, stream>>>(Wq_w, W_bf, n8);
  gemm_nt_bf16<<<gg, 256, 0, stream>>>(roi_bf, W_bf, Wq_b, Qb, F_, F_);
  cvt_bf16<<<2048, 256, 0, stream>>>(Wk_w, W_bf, n8);
  gemm_nt_bf16<<<gg, 256, 0, stream>>>(ref_bf, W_bf, Wk_b, Kb, F_, F_);
  cvt_bf16<<<2048, 256, 0, stream>>>(Wv_w, W_bf, n8);
  // V^T for free: C[f][m] = sum_k Wv[f][k] * ref[m][k]
  gemm_nt_bf16<<<gg, 256, 0, stream>>>(W_bf, ref_bf, nullptr, Vtb, F_, M_);

  attn_mfma<<<dim3(N_ / 64, G_), 256, 0, stream>>>(Qb, Kb, Vtb, Wv_b, out);
}